// Round 2
// baseline (249.774 us; speedup 1.0000x reference)
//
#include <hip/hip_runtime.h>

#define NZ 1e-5f
#define PF 8  // prefetch depth (timesteps of forcing held in registers)

__device__ __forceinline__ float fast_exp2(float x) {
#if __has_builtin(__builtin_amdgcn_exp2f)
    return __builtin_amdgcn_exp2f(x);   // v_exp_f32
#else
    return exp2f(x);
#endif
}

__device__ __forceinline__ float fast_log2(float x) {
#if __has_builtin(__builtin_amdgcn_logf)
    return __builtin_amdgcn_logf(x);    // v_log_f32 (base-2)
#else
    return log2f(x);
#endif
}

__global__ __launch_bounds__(64) void hbv_kernel(
    const float* __restrict__ precip,
    const float* __restrict__ temp,
    const float* __restrict__ pet,
    const float* __restrict__ phy,
    float* __restrict__ out,
    int G, int T)
{
    const int g = blockIdx.x * 64 + threadIdx.x;
    if (g >= G) return;

    // Parameter bounds (compile-time constants, folded)
    const float lo[14] = {1.0f, 50.0f, 0.05f, 0.01f, 0.001f, 0.2f, 0.0f,
                          0.0f, -2.5f, 0.5f, 0.0f, 0.0f, 0.3f, 0.0f};
    const float hi[14] = {6.0f, 1000.0f, 0.9f, 0.5f, 0.2f, 1.0f, 10.0f,
                          100.0f, 2.5f, 10.0f, 0.1f, 0.2f, 5.0f, 1.0f};
    float p[14];
#pragma unroll
    for (int i = 0; i < 14; ++i)
        p[i] = lo[i] + phy[g * 14 + i] * (hi[i] - lo[i]);

    const float BETA = p[0], FC = p[1], K0 = p[2], K1 = p[3], K2 = p[4];
    const float LP = p[5], PERCp = p[6], UZL = p[7], TT = p[8], CFMAX = p[9];
    const float CFR = p[10], CWH = p[11], BETAET = p[12], C = p[13];
    const float invFC   = 1.0f / FC;
    const float invLPFC = 1.0f / (LP * FC);
    const float CFRX    = CFR * CFMAX;

    // State (registers for the whole scan)
    float SP = NZ, MW = NZ, SM = NZ, SUZ = NZ, SLZ = NZ;

    // Register ring buffer of prefetched forcings
    float prb[PF], tmb[PF], peb[PF];
#pragma unroll
    for (int j = 0; j < PF; ++j) {
        int tc = (j < T) ? j : (T - 1);
        int idx = tc * G + g;
        prb[j] = precip[idx];
        tmb[j] = temp[idx];
        peb[j] = pet[idx];
    }

    for (int t0 = 0; t0 < T; t0 += PF) {
#pragma unroll
        for (int j = 0; j < PF; ++j) {
            const int t = t0 + j;
            // consume buffered forcings
            const float pr = prb[j], tm = tmb[j], pe = peb[j];
            // issue prefetch for t + PF (clamped index: branch-free, stays in flight)
            {
                int tn = t + PF;
                int tc = (tn < T) ? tn : (T - 1);
                int idx = tc * G + g;
                prb[j] = precip[idx];
                tmb[j] = temp[idx];
                peb[j] = pet[idx];
            }

            // --- HBV step (mirrors reference op order exactly) ---
            const float RAIN = (tm >= TT) ? pr : 0.0f;
            const float SNOW = pr - RAIN;
            SP += SNOW;
            float melt = fminf(fmaxf(CFMAX * (tm - TT), 0.0f), SP);
            MW += melt;
            SP -= melt;
            float refr = fminf(fmaxf(CFRX * (TT - tm), 0.0f), MW);
            SP += refr;
            MW -= refr;
            float tosoil = fmaxf(MW - CWH * SP, 0.0f);
            MW -= tosoil;
            // soil_wetness = clip((SM/FC)^BETA, 0, 1); base > 0 always
            float sw = fminf(fast_exp2(BETA * fast_log2(SM * invFC)), 1.0f);
            float rt = RAIN + tosoil;
            float recharge = rt * sw;
            SM += rt - recharge;
            float excess = fmaxf(SM - FC, 0.0f);
            SM -= excess;
            float ef = fminf(fast_exp2(BETAET * fast_log2(SM * invLPFC)), 1.0f);
            float ETact = fminf(SM, pe * ef);
            SM = fmaxf(SM - ETact, NZ);
            float cap = fminf(SLZ, C * SLZ * (1.0f - fminf(SM * invFC, 1.0f)));
            SM = fmaxf(SM + cap, NZ);
            SLZ = fmaxf(SLZ - cap, NZ);
            SUZ += recharge + excess;
            float PERC = fminf(SUZ, PERCp);
            SUZ -= PERC;
            float Q0 = K0 * fmaxf(SUZ - UZL, 0.0f);
            SUZ -= Q0;
            float Q1 = K1 * SUZ;
            SUZ -= Q1;
            SLZ = fmaxf(SLZ + PERC, 0.0f);
            float Q2 = K2 * SLZ;
            SLZ -= Q2;

            if (t < T)  // uniform guard: last chunk overruns T by (PF - T%PF)
                out[t * G + g] = Q0 + Q1 + Q2;
        }
    }
}

extern "C" void kernel_launch(void* const* d_in, const int* in_sizes, int n_in,
                              void* d_out, int out_size, void* d_ws, size_t ws_size,
                              hipStream_t stream) {
    const float* precip = (const float*)d_in[0];
    const float* temp   = (const float*)d_in[1];
    const float* pet    = (const float*)d_in[2];
    const float* phy    = (const float*)d_in[3];
    float* out = (float*)d_out;

    const int G = in_sizes[3] / 14;   // 50000
    const int T = in_sizes[0] / G;    // 365

    dim3 block(64);
    dim3 grid((G + 63) / 64);         // 782 blocks -> all 256 CUs covered
    hbv_kernel<<<grid, block, 0, stream>>>(precip, temp, pet, phy, out, G, T);
}

// Round 3
// 247.584 us; speedup vs baseline: 1.0088x; 1.0088x over previous
//
#include <hip/hip_runtime.h>

#define NZ 1e-5f
#define PF 8  // prefetch depth (timesteps of forcing held in registers)

__device__ __forceinline__ float fast_exp2(float x) {
#if __has_builtin(__builtin_amdgcn_exp2f)
    return __builtin_amdgcn_exp2f(x);   // v_exp_f32
#else
    return exp2f(x);
#endif
}

__device__ __forceinline__ float fast_log2(float x) {
#if __has_builtin(__builtin_amdgcn_logf)
    return __builtin_amdgcn_logf(x);    // v_log_f32 (base-2)
#else
    return log2f(x);
#endif
}

// (64, 1): min 1 wave/EU -> maximal VGPR budget. Only 781 waves exist in the
// whole problem (<1 wave/SIMD), so capping VGPRs for occupancy is pure loss —
// the default cap at VGPR=36 spilled the prefetch ring to scratch (R2: 68% stall).
__global__ __launch_bounds__(64, 1) void hbv_kernel(
    const float* __restrict__ precip,
    const float* __restrict__ temp,
    const float* __restrict__ pet,
    const float* __restrict__ phy,
    float* __restrict__ out,
    int G, int T)
{
    const int g = blockIdx.x * 64 + threadIdx.x;
    if (g >= G) return;

    // Parameter bounds (compile-time constants, folded)
    const float lo[14] = {1.0f, 50.0f, 0.05f, 0.01f, 0.001f, 0.2f, 0.0f,
                          0.0f, -2.5f, 0.5f, 0.0f, 0.0f, 0.3f, 0.0f};
    const float hi[14] = {6.0f, 1000.0f, 0.9f, 0.5f, 0.2f, 1.0f, 10.0f,
                          100.0f, 2.5f, 10.0f, 0.1f, 0.2f, 5.0f, 1.0f};
    float p[14];
#pragma unroll
    for (int i = 0; i < 14; ++i)
        p[i] = lo[i] + phy[g * 14 + i] * (hi[i] - lo[i]);

    const float BETA = p[0], FC = p[1], K0 = p[2], K1 = p[3], K2 = p[4];
    const float LP = p[5], PERCp = p[6], UZL = p[7], TT = p[8], CFMAX = p[9];
    const float CFR = p[10], CWH = p[11], BETAET = p[12], C = p[13];
    const float invFC   = 1.0f / FC;
    const float invLPFC = 1.0f / (LP * FC);
    const float CFRX    = CFR * CFMAX;

    // State (registers for the whole scan)
    float SP = NZ, MW = NZ, SM = NZ, SUZ = NZ, SLZ = NZ;

    // Register ring buffer of prefetched forcings
    float prb[PF], tmb[PF], peb[PF];
#pragma unroll
    for (int j = 0; j < PF; ++j) {
        int tc = (j < T) ? j : (T - 1);
        int idx = tc * G + g;
        prb[j] = precip[idx];
        tmb[j] = temp[idx];
        peb[j] = pet[idx];
    }

    for (int t0 = 0; t0 < T; t0 += PF) {
#pragma unroll
        for (int j = 0; j < PF; ++j) {
            const int t = t0 + j;
            // consume buffered forcings
            const float pr = prb[j], tm = tmb[j], pe = peb[j];
            // issue prefetch for t + PF (clamped index: branch-free, stays in flight)
            {
                int tn = t + PF;
                int tc = (tn < T) ? tn : (T - 1);
                int idx = tc * G + g;
                prb[j] = precip[idx];
                tmb[j] = temp[idx];
                peb[j] = pet[idx];
            }

            // --- HBV step (mirrors reference op order exactly) ---
            const float RAIN = (tm >= TT) ? pr : 0.0f;
            const float SNOW = pr - RAIN;
            SP += SNOW;
            float melt = fminf(fmaxf(CFMAX * (tm - TT), 0.0f), SP);
            MW += melt;
            SP -= melt;
            float refr = fminf(fmaxf(CFRX * (TT - tm), 0.0f), MW);
            SP += refr;
            MW -= refr;
            float tosoil = fmaxf(MW - CWH * SP, 0.0f);
            MW -= tosoil;
            // soil_wetness = clip((SM/FC)^BETA, 0, 1); base > 0 always
            float sw = fminf(fast_exp2(BETA * fast_log2(SM * invFC)), 1.0f);
            float rt = RAIN + tosoil;
            float recharge = rt * sw;
            SM += rt - recharge;
            float excess = fmaxf(SM - FC, 0.0f);
            SM -= excess;
            float ef = fminf(fast_exp2(BETAET * fast_log2(SM * invLPFC)), 1.0f);
            float ETact = fminf(SM, pe * ef);
            SM = fmaxf(SM - ETact, NZ);
            float cap = fminf(SLZ, C * SLZ * (1.0f - fminf(SM * invFC, 1.0f)));
            SM = fmaxf(SM + cap, NZ);
            SLZ = fmaxf(SLZ - cap, NZ);
            SUZ += recharge + excess;
            float PERC = fminf(SUZ, PERCp);
            SUZ -= PERC;
            float Q0 = K0 * fmaxf(SUZ - UZL, 0.0f);
            SUZ -= Q0;
            float Q1 = K1 * SUZ;
            SUZ -= Q1;
            SLZ = fmaxf(SLZ + PERC, 0.0f);
            float Q2 = K2 * SLZ;
            SLZ -= Q2;

            if (t < T)  // uniform guard: last chunk overruns T by (PF - T%PF)
                out[t * G + g] = Q0 + Q1 + Q2;
        }
    }
}

extern "C" void kernel_launch(void* const* d_in, const int* in_sizes, int n_in,
                              void* d_out, int out_size, void* d_ws, size_t ws_size,
                              hipStream_t stream) {
    const float* precip = (const float*)d_in[0];
    const float* temp   = (const float*)d_in[1];
    const float* pet    = (const float*)d_in[2];
    const float* phy    = (const float*)d_in[3];
    float* out = (float*)d_out;

    const int G = in_sizes[3] / 14;   // 50000
    const int T = in_sizes[0] / G;    // 365

    dim3 block(64);
    dim3 grid((G + 63) / 64);         // 782 blocks -> all 256 CUs covered
    hbv_kernel<<<grid, block, 0, stream>>>(precip, temp, pet, phy, out, G, T);
}